// Round 1
// baseline (449.550 us; speedup 1.0000x reference)
//
#include <hip/hip_runtime.h>
#include <math.h>

#define NBINS 15

// One wave (64 lanes) per row. Lanes 0..P-1 load a float2 each (C even, C<=128).
// Butterfly reductions give every lane (conf, pred); lane l accumulates bin l
// in registers across the whole grid-stride loop. Block combine in LDS, then
// 45 global atomics per block into d_ws bins [15][3] = {count, sum_conf, sum_acc}.
__global__ __launch_bounds__(256) void ce_main(const float* __restrict__ logits,
                                               const int* __restrict__ labels,
                                               float* __restrict__ gbins,
                                               int N, int C) {
    const int lane = threadIdx.x & 63;
    const int wid = threadIdx.x >> 6;
    const int wavesPerBlock = blockDim.x >> 6;
    const int gwave = blockIdx.x * wavesPerBlock + wid;
    const int nwaves = gridDim.x * wavesPerBlock;

    float bc = 0.f, bsc = 0.f, bsa = 0.f;   // this lane's bin accumulators

    const int P = C >> 1;                    // float2 pairs per row (C even)

    for (int row = gwave; row < N; row += nwaves) {
        const float* rp = logits + (size_t)row * (size_t)C;
        float v0 = -INFINITY, v1 = -INFINITY;
        int c0 = 0x7fffffff, c1 = 0x7fffffff;
        if (lane < P) {
            float2 v = *reinterpret_cast<const float2*>(rp + 2 * lane);
            v0 = v.x; v1 = v.y;
            c0 = 2 * lane; c1 = 2 * lane + 1;
        }

        // per-lane max with first-occurrence tie-break
        float m; int mi;
        if (v1 > v0) { m = v1; mi = c1; } else { m = v0; mi = c0; }

        // wave argmax (all lanes converge)
        #pragma unroll
        for (int off = 1; off < 64; off <<= 1) {
            float om = __shfl_xor(m, off);
            int   oi = __shfl_xor(mi, off);
            if (om > m || (om == m && oi < mi)) { m = om; mi = oi; }
        }

        // sum of exp(x - max); invalid lanes contribute exp(-inf)=0
        float e = __expf(v0 - m) + __expf(v1 - m);
        #pragma unroll
        for (int off = 1; off < 64; off <<= 1) e += __shfl_xor(e, off);

        float conf = 1.0f / e;               // == max softmax prob
        int lab = labels[row];
        float acc = (mi == lab) ? 1.0f : 0.0f;

        int b = (int)ceilf(conf * (float)NBINS) - 1;
        b = min(max(b, 0), NBINS - 1);

        if (lane == b) { bc += 1.0f; bsc += conf; bsa += acc; }
    }

    // block combine
    __shared__ float sb[NBINS * 3];
    if (threadIdx.x < NBINS * 3) sb[threadIdx.x] = 0.f;
    __syncthreads();
    if (lane < NBINS) {
        atomicAdd(&sb[lane * 3 + 0], bc);
        atomicAdd(&sb[lane * 3 + 1], bsc);
        atomicAdd(&sb[lane * 3 + 2], bsa);
    }
    __syncthreads();
    if (threadIdx.x < NBINS * 3) {
        float v = sb[threadIdx.x];
        if (v != 0.f) atomicAdd(&gbins[threadIdx.x], v);
    }
}

__global__ void ce_final(const float* __restrict__ gbins, float* __restrict__ out,
                         float inv_n) {
    int t = threadIdx.x;
    float gap = 0.f, w = 0.f;
    bool ne = false;
    if (t < NBINS) {
        float c = gbins[t * 3 + 0];
        float sc = gbins[t * 3 + 1];
        float sa = gbins[t * 3 + 2];
        if (c > 0.f) { ne = true; gap = fabsf(sc / c - sa / c); w = c; }
    }
    float ece = ne ? gap * w * inv_n : 0.f;
    float mce = ne ? gap : -INFINITY;
    #pragma unroll
    for (int off = 1; off < 64; off <<= 1) {
        ece += __shfl_xor(ece, off);
        mce = fmaxf(mce, __shfl_xor(mce, off));
    }
    if (t == 0) {
        out[0] = ece;
        out[1] = (mce == -INFINITY) ? 1.0f : mce;
    }
}

extern "C" void kernel_launch(void* const* d_in, const int* in_sizes, int n_in,
                              void* d_out, int out_size, void* d_ws, size_t ws_size,
                              hipStream_t stream) {
    const float* logits = (const float*)d_in[0];
    const int* labels = (const int*)d_in[1];
    int N = in_sizes[1];
    int C = in_sizes[0] / in_sizes[1];   // 100

    float* gbins = (float*)d_ws;
    hipMemsetAsync(gbins, 0, NBINS * 3 * sizeof(float), stream);

    ce_main<<<2048, 256, 0, stream>>>(logits, labels, gbins, N, C);
    ce_final<<<1, 64, 0, stream>>>(gbins, (float*)d_out, 1.0f / (float)N);
}

// Round 2
// 268.474 us; speedup vs baseline: 1.6745x; 1.6745x over previous
//
#include <hip/hip_runtime.h>
#include <math.h>

#define NBINS 15

// One THREAD per row: online softmax-max scan of 100 floats via 25 float4
// loads. No cross-lane ops (round-1 was DS-pipe bound at 18 ds_bpermute/row).
// Per-block LDS histogram (15 bins x {count, sum_conf, sum_acc}), then global
// atomics once per block.
template<int NQ>
__global__ __launch_bounds__(256) void ce_rows(const float* __restrict__ logits,
                                               const int* __restrict__ labels,
                                               float* __restrict__ gbins, int N) {
    __shared__ float sb[NBINS * 3];
    if (threadIdx.x < NBINS * 3) sb[threadIdx.x] = 0.f;
    __syncthreads();

    const int r = blockIdx.x * blockDim.x + threadIdx.x;
    if (r < N) {
        const float4* rp = reinterpret_cast<const float4*>(logits + (size_t)r * (NQ * 4));
        float m = -INFINITY, s = 0.f;
        int arg = 0;
        #pragma unroll
        for (int k = 0; k < NQ; ++k) {
            float4 v = rp[k];
            // quad max, first-occurrence index within quad
            float qm = v.x; int qa = 4 * k;
            if (v.y > qm) { qm = v.y; qa = 4 * k + 1; }
            if (v.z > qm) { qm = v.z; qa = 4 * k + 2; }
            if (v.w > qm) { qm = v.w; qa = 4 * k + 3; }
            // online max update (strict > keeps earliest occurrence across quads)
            // first iter: m=-inf -> expf(-inf)=0, s stays 0: correct.
            if (qm > m) { s *= __expf(m - qm); m = qm; arg = qa; }
            s += __expf(v.x - m) + __expf(v.y - m) + __expf(v.z - m) + __expf(v.w - m);
        }
        float conf = 1.0f / s;                 // max softmax prob
        float acc = (arg == labels[r]) ? 1.0f : 0.0f;
        int b = (int)ceilf(conf * (float)NBINS) - 1;
        b = min(max(b, 0), NBINS - 1);
        atomicAdd(&sb[b * 3 + 0], 1.0f);
        atomicAdd(&sb[b * 3 + 1], conf);
        if (acc != 0.f) atomicAdd(&sb[b * 3 + 2], acc);
    }
    __syncthreads();
    if (threadIdx.x < NBINS * 3) {
        float v = sb[threadIdx.x];
        if (v != 0.f) atomicAdd(&gbins[threadIdx.x], v);
    }
}

// Generic fallback for C != 100 (scalar loop, same semantics).
__global__ __launch_bounds__(256) void ce_rows_generic(const float* __restrict__ logits,
                                                       const int* __restrict__ labels,
                                                       float* __restrict__ gbins,
                                                       int N, int C) {
    __shared__ float sb[NBINS * 3];
    if (threadIdx.x < NBINS * 3) sb[threadIdx.x] = 0.f;
    __syncthreads();

    const int r = blockIdx.x * blockDim.x + threadIdx.x;
    if (r < N) {
        const float* rp = logits + (size_t)r * (size_t)C;
        float m = -INFINITY, s = 0.f;
        int arg = 0;
        for (int k = 0; k < C; ++k) {
            float x = rp[k];
            if (x > m) { s *= __expf(m - x); m = x; arg = k; }
            s += __expf(x - m);
        }
        float conf = 1.0f / s;
        float acc = (arg == labels[r]) ? 1.0f : 0.0f;
        int b = (int)ceilf(conf * (float)NBINS) - 1;
        b = min(max(b, 0), NBINS - 1);
        atomicAdd(&sb[b * 3 + 0], 1.0f);
        atomicAdd(&sb[b * 3 + 1], conf);
        if (acc != 0.f) atomicAdd(&sb[b * 3 + 2], acc);
    }
    __syncthreads();
    if (threadIdx.x < NBINS * 3) {
        float v = sb[threadIdx.x];
        if (v != 0.f) atomicAdd(&gbins[threadIdx.x], v);
    }
}

__global__ void ce_final(const float* __restrict__ gbins, float* __restrict__ out,
                         float inv_n) {
    int t = threadIdx.x;
    float gap = 0.f, w = 0.f;
    bool ne = false;
    if (t < NBINS) {
        float c = gbins[t * 3 + 0];
        float sc = gbins[t * 3 + 1];
        float sa = gbins[t * 3 + 2];
        if (c > 0.f) { ne = true; gap = fabsf(sc / c - sa / c); w = c; }
    }
    float ece = ne ? gap * w * inv_n : 0.f;
    float mce = ne ? gap : -INFINITY;
    #pragma unroll
    for (int off = 1; off < 64; off <<= 1) {
        ece += __shfl_xor(ece, off);
        mce = fmaxf(mce, __shfl_xor(mce, off));
    }
    if (t == 0) {
        out[0] = ece;
        out[1] = (mce == -INFINITY) ? 1.0f : mce;
    }
}

extern "C" void kernel_launch(void* const* d_in, const int* in_sizes, int n_in,
                              void* d_out, int out_size, void* d_ws, size_t ws_size,
                              hipStream_t stream) {
    const float* logits = (const float*)d_in[0];
    const int* labels = (const int*)d_in[1];
    int N = in_sizes[1];
    int C = in_sizes[0] / in_sizes[1];   // 100

    float* gbins = (float*)d_ws;
    hipMemsetAsync(gbins, 0, NBINS * 3 * sizeof(float), stream);

    int nblocks = (N + 255) / 256;
    if (C == 100) {
        ce_rows<25><<<nblocks, 256, 0, stream>>>(logits, labels, gbins, N);
    } else {
        ce_rows_generic<<<nblocks, 256, 0, stream>>>(logits, labels, gbins, N, C);
    }
    ce_final<<<1, 64, 0, stream>>>(gbins, (float*)d_out, 1.0f / (float)N);
}

// Round 4
// 166.807 us; speedup vs baseline: 2.6950x; 1.6095x over previous
//
#include <hip/hip_runtime.h>
#include <math.h>

#define NBINS 15

// DPP quad_perm helpers (pure VALU cross-lane within groups of 4 lanes).
// ctrl must be a compile-time constant -> template parameter.
template<int CTRL>
__device__ __forceinline__ float dpp_f(float x) {
    return __int_as_float(__builtin_amdgcn_update_dpp(
        0, __float_as_int(x), CTRL, 0xF, 0xF, true));
}
template<int CTRL>
__device__ __forceinline__ int dpp_i(int x) {
    return __builtin_amdgcn_update_dpp(0, x, CTRL, 0xF, 0xF, true);
}

#define QP_XOR1 0xB1   // quad_perm {1,0,3,2}
#define QP_XOR2 0x4E   // quad_perm {2,3,0,1}

// 4 lanes per row. Lane q of a quad loads float4 quads {q, 4+q, 8+q, ...} of
// its row -> each instruction covers one contiguous 64B segment per row
// (coalesced; every cache line fetched once, fully consumed immediately).
// Per-lane online softmax (max, argmax-first, sum of exp), then quad combine
// via 2 DPP quad_perm butterfly steps (VALU only; no DS pipe).
__global__ __launch_bounds__(256) void ce_rows100(const float* __restrict__ logits,
                                                  const int* __restrict__ labels,
                                                  float* __restrict__ gbins, int N) {
    __shared__ float sb[NBINS * 3];
    if (threadIdx.x < NBINS * 3) sb[threadIdx.x] = 0.f;
    __syncthreads();

    const int lane = threadIdx.x & 63;
    const int q = lane & 3;        // lane within quad
    const int rq = lane >> 2;      // row within 16-row chunk
    const int gw = (blockIdx.x * blockDim.x + threadIdx.x) >> 6;
    const int nw = (gridDim.x * blockDim.x) >> 6;
    const int nchunks = (N + 15) >> 4;

    for (int chunk = gw; chunk < nchunks; chunk += nw) {
        const int row = chunk * 16 + rq;
        const bool valid = row < N;

        float m = -INFINITY, s = 0.f;
        int arg = 0;

        if (valid) {
            const float4* rp = reinterpret_cast<const float4*>(logits) + (size_t)row * 25;
            #pragma unroll
            for (int k = 0; k < 6; ++k) {
                const int qi = 4 * k + q;          // quad index in row, < 24
                float4 v = rp[qi];
                const int bi = qi * 4;
                { float x = v.x; if (x > m) { s *= __expf(m - x); m = x; arg = bi;     } s += __expf(x - m); }
                { float x = v.y; if (x > m) { s *= __expf(m - x); m = x; arg = bi + 1; } s += __expf(x - m); }
                { float x = v.z; if (x > m) { s *= __expf(m - x); m = x; arg = bi + 2; } s += __expf(x - m); }
                { float x = v.w; if (x > m) { s *= __expf(m - x); m = x; arg = bi + 3; } s += __expf(x - m); }
            }
            if (q == 0) {                           // quad 24 (elements 96..99)
                float4 v = rp[24];
                { float x = v.x; if (x > m) { s *= __expf(m - x); m = x; arg = 96; } s += __expf(x - m); }
                { float x = v.y; if (x > m) { s *= __expf(m - x); m = x; arg = 97; } s += __expf(x - m); }
                { float x = v.z; if (x > m) { s *= __expf(m - x); m = x; arg = 98; } s += __expf(x - m); }
                { float x = v.w; if (x > m) { s *= __expf(m - x); m = x; arg = 99; } s += __expf(x - m); }
            }
        }

        // quad argmax butterfly (first-occurrence: equal max -> smaller index)
        const float ml = m;
        float M = m; int A = arg;
        {
            float t = dpp_f<QP_XOR1>(M); int ti = dpp_i<QP_XOR1>(A);
            if (t > M || (t == M && ti < A)) { M = t; A = ti; }
            t = dpp_f<QP_XOR2>(M); ti = dpp_i<QP_XOR2>(A);
            if (t > M || (t == M && ti < A)) { M = t; A = ti; }
        }
        // quad sum of s_l * exp(m_l - M)
        float sc = s * __expf(ml - M);
        sc += dpp_f<QP_XOR1>(sc);
        sc += dpp_f<QP_XOR2>(sc);

        if (valid && q == 0) {
            const float conf = 1.0f / sc;          // max softmax prob
            const int lab = labels[row];
            int b = (int)ceilf(conf * (float)NBINS) - 1;
            b = min(max(b, 0), NBINS - 1);
            atomicAdd(&sb[b * 3 + 0], 1.0f);
            atomicAdd(&sb[b * 3 + 1], conf);
            if (A == lab) atomicAdd(&sb[b * 3 + 2], 1.0f);
        }
    }

    __syncthreads();
    if (threadIdx.x < NBINS * 3) {
        float v = sb[threadIdx.x];
        if (v != 0.f) atomicAdd(&gbins[threadIdx.x], v);
    }
}

// Generic fallback for C != 100 (scalar per-thread, correct for any C).
__global__ __launch_bounds__(256) void ce_rows_generic(const float* __restrict__ logits,
                                                       const int* __restrict__ labels,
                                                       float* __restrict__ gbins,
                                                       int N, int C) {
    __shared__ float sb[NBINS * 3];
    if (threadIdx.x < NBINS * 3) sb[threadIdx.x] = 0.f;
    __syncthreads();

    const int r = blockIdx.x * blockDim.x + threadIdx.x;
    if (r < N) {
        const float* rp = logits + (size_t)r * (size_t)C;
        float m = -INFINITY, s = 0.f;
        int arg = 0;
        for (int k = 0; k < C; ++k) {
            float x = rp[k];
            if (x > m) { s *= __expf(m - x); m = x; arg = k; }
            s += __expf(x - m);
        }
        float conf = 1.0f / s;
        int b = (int)ceilf(conf * (float)NBINS) - 1;
        b = min(max(b, 0), NBINS - 1);
        atomicAdd(&sb[b * 3 + 0], 1.0f);
        atomicAdd(&sb[b * 3 + 1], conf);
        if (arg == labels[r]) atomicAdd(&sb[b * 3 + 2], 1.0f);
    }
    __syncthreads();
    if (threadIdx.x < NBINS * 3) {
        float v = sb[threadIdx.x];
        if (v != 0.f) atomicAdd(&gbins[threadIdx.x], v);
    }
}

__global__ void ce_final(const float* __restrict__ gbins, float* __restrict__ out,
                         float inv_n) {
    int t = threadIdx.x;
    float gap = 0.f, w = 0.f;
    bool ne = false;
    if (t < NBINS) {
        float c = gbins[t * 3 + 0];
        float sc = gbins[t * 3 + 1];
        float sa = gbins[t * 3 + 2];
        if (c > 0.f) { ne = true; gap = fabsf(sc / c - sa / c); w = c; }
    }
    float ece = ne ? gap * w * inv_n : 0.f;
    float mce = ne ? gap : -INFINITY;
    #pragma unroll
    for (int off = 1; off < 64; off <<= 1) {
        ece += __shfl_xor(ece, off);
        mce = fmaxf(mce, __shfl_xor(mce, off));
    }
    if (t == 0) {
        out[0] = ece;
        out[1] = (mce == -INFINITY) ? 1.0f : mce;
    }
}

extern "C" void kernel_launch(void* const* d_in, const int* in_sizes, int n_in,
                              void* d_out, int out_size, void* d_ws, size_t ws_size,
                              hipStream_t stream) {
    const float* logits = (const float*)d_in[0];
    const int* labels = (const int*)d_in[1];
    int N = in_sizes[1];
    int C = in_sizes[0] / in_sizes[1];   // 100

    float* gbins = (float*)d_ws;
    (void)hipMemsetAsync(gbins, 0, NBINS * 3 * sizeof(float), stream);

    if (C == 100) {
        ce_rows100<<<2048, 256, 0, stream>>>(logits, labels, gbins, N);
    } else {
        ce_rows_generic<<<(N + 255) / 256, 256, 0, stream>>>(logits, labels, gbins, N, C);
    }
    ce_final<<<1, 64, 0, stream>>>(gbins, (float*)d_out, 1.0f / (float)N);
}